// Round 5
// baseline (1745.132 us; speedup 1.0000x reference)
//
#include <hip/hip_runtime.h>
#include <math.h>

#define NL 4
#define DMODEL 768
#define DINNER 1536
#define DSTATE 16
#define DCONV 4
#define DTRANK 48
#define BATCH 2
#define SEQLEN 1024
#define MTOK (BATCH*SEQLEN)      // 2048
#define XDIM 80                  // DT_RANK + 2*D_STATE
#define KPAD 64                  // DTRANK padded for MFMA
#define NPAD 96                  // XDIM padded for MFMA (3x32)
#define KS2 16                   // split-K slices for GEMM2
#define SCHUNK 64                // scan chunks per sequence
#define SCLEN 16                 // timesteps per chunk

typedef __bf16 bf16x8 __attribute__((ext_vector_type(8)));
typedef float f32x4 __attribute__((ext_vector_type(4)));

__device__ __forceinline__ void splitbf(float f, unsigned short& hi, unsigned short& lo) {
    unsigned uh = __float_as_uint(f);
    unsigned rh = uh + (0x7fffu + ((uh >> 16) & 1u));
    unsigned short h = (unsigned short)(rh >> 16);
    float fh = __uint_as_float(((unsigned)h) << 16);
    float r = f - fh;
    unsigned ul = __float_as_uint(r);
    unsigned rl = ul + (0x7fffu + ((ul >> 16) & 1u));
    hi = h;
    lo = (unsigned short)(rl >> 16);
}

__device__ __forceinline__ void splitbf4(float4 v, ushort4& h, ushort4& l) {
    splitbf(v.x, h.x, l.x);
    splitbf(v.y, h.y, l.y);
    splitbf(v.z, h.z, l.z);
    splitbf(v.w, h.w, l.w);
}

__device__ __forceinline__ float bf2f(unsigned short h) {
    return __uint_as_float(((unsigned)h) << 16);
}

__device__ __forceinline__ void gload_lds16(const void* g, void* l) {
    __builtin_amdgcn_global_load_lds(
        (const __attribute__((address_space(1))) unsigned*)g,
        (__attribute__((address_space(3))) unsigned*)l, 16, 0, 0);
}

// ---------------------------------------------------------------------------
// Per-layer prep: all weight splits (+padding) and dt pad-zero in ONE kernel.
// ---------------------------------------------------------------------------
#define N_IPW (2 * DINNER * DMODEL / 4)
#define N_OPW (DMODEL * DINNER / 4)
#define N_XPW (NPAD * DINNER / 4)
#define N_DPW (DINNER * KPAD / 4)
#define N_DTP (MTOK * (KPAD - DTRANK) / 4)
#define N_PREP (N_IPW + N_OPW + N_XPW + N_DPW + N_DTP)
#define N_XSPL (MTOK * DMODEL / 4)

template<int WITHX>
__global__ __launch_bounds__(256) void prep_kernel(
    const float* __restrict__ ipw_l, const float* __restrict__ opw_l,
    const float* __restrict__ xpw_l, const float* __restrict__ dpw_l,
    const float* __restrict__ x,
    unsigned short* __restrict__ wih, unsigned short* __restrict__ wil,
    unsigned short* __restrict__ woh, unsigned short* __restrict__ wol,
    unsigned short* __restrict__ wxh, unsigned short* __restrict__ wxl,
    unsigned short* __restrict__ wdh, unsigned short* __restrict__ wdl,
    unsigned short* __restrict__ dth, unsigned short* __restrict__ dtl,
    unsigned short* __restrict__ ah, unsigned short* __restrict__ al)
{
    int i = blockIdx.x * 256 + threadIdx.x;
    if (i < N_IPW) {
        float4 v = ((const float4*)ipw_l)[i];
        ushort4 h, l;
        splitbf4(v, h, l);
        ((ushort4*)wih)[i] = h;
        ((ushort4*)wil)[i] = l;
        return;
    }
    i -= N_IPW;
    if (i < N_OPW) {
        float4 v = ((const float4*)opw_l)[i];
        ushort4 h, l;
        splitbf4(v, h, l);
        ((ushort4*)woh)[i] = h;
        ((ushort4*)wol)[i] = l;
        return;
    }
    i -= N_OPW;
    if (i < N_XPW) {
        int e = i * 4;
        int row = e / DINNER, col = e % DINNER;
        ushort4 h = {0, 0, 0, 0}, l = {0, 0, 0, 0};
        if (row < XDIM) {
            float4 v = *(const float4*)(xpw_l + (size_t)row * DINNER + col);
            splitbf4(v, h, l);
        }
        ((ushort4*)wxh)[i] = h;
        ((ushort4*)wxl)[i] = l;
        return;
    }
    i -= N_XPW;
    if (i < N_DPW) {
        int e = i * 4;
        int row = e >> 6, col = e & 63;
        ushort4 h = {0, 0, 0, 0}, l = {0, 0, 0, 0};
        if (col < DTRANK) {
            float4 v = *(const float4*)(dpw_l + (size_t)row * DTRANK + col);
            splitbf4(v, h, l);
        }
        ((ushort4*)wdh)[i] = h;
        ((ushort4*)wdl)[i] = l;
        return;
    }
    i -= N_DPW;
    if (i < N_DTP) {
        int e = i * 4;
        int row = e >> 4, col = DTRANK + (e & 15);
        int o = (row * KPAD + col) / 4;
        ushort4 z = {0, 0, 0, 0};
        ((ushort4*)dth)[o] = z;
        ((ushort4*)dtl)[o] = z;
        return;
    }
    if (WITHX) {
        i -= N_DTP;
        if (i < N_XSPL) {
            float4 v = ((const float4*)x)[i];
            ushort4 h, l;
            splitbf4(v, h, l);
            ((ushort4*)ah)[i] = h;
            ((ushort4*)al)[i] = l;
        }
    }
}

// ---------------------------------------------------------------------------
// Pre-split 3-pass bf16 MFMA GEMM, XOR-swizzled LDS (bank-conflict-free):
// LDS slot for 16B chunk c of row r is (c ^ ((r>>1)&3)); staging permutes the
// global source chunk per lane (still 64B-coalesced, lane-linear LDS dest).
// C[M,N] = (Ah+Al)@(Wh+Wl)^T dropping Al*Wl. blockIdx.z = split-K slice.
// EPI 0: plain store; EPI 2: softplus(acc + bias[col]). Cols >= nclip dropped.
// ---------------------------------------------------------------------------
template<int BM, int BN, int EPI>
__global__ __launch_bounds__(256, 2) void gemm_pre(
    const unsigned short* __restrict__ Ah, const unsigned short* __restrict__ Al, int lda,
    const unsigned short* __restrict__ Wh, const unsigned short* __restrict__ Wl, int ldw,
    float* __restrict__ C, int ldc, int Klen, size_t zstride, int nclip,
    const float* __restrict__ bias)
{
    constexpr int BK = 32;
    constexpr int MT = BM / 32, NT = BN / 32;
    constexpr int ACH = BM * 4;   // 16B chunks per tile
    constexpr int WCH = BN * 4;
    __shared__ unsigned short sAh[BM * BK];
    __shared__ unsigned short sAl[BM * BK];
    __shared__ unsigned short sWh[BN * BK];
    __shared__ unsigned short sWl[BN * BK];

    const int tid = threadIdx.x;
    const int m0 = blockIdx.y * BM, n0 = blockIdx.x * BN;
    const int kbase = blockIdx.z * Klen;
    C += (size_t)blockIdx.z * zstride;
    const int lane = tid & 63, wave = tid >> 6;
    const int wr = wave >> 1, wc = wave & 1;
    const int wm0 = wr * (BM / 2), wn0 = wc * (BN / 2);
    const int lrow = lane & 15, lq = lane >> 4;

    f32x4 acc[MT][NT];
    #pragma unroll
    for (int mt = 0; mt < MT; mt++)
        #pragma unroll
        for (int nt = 0; nt < NT; nt++) {
            f32x4 z = {0.f, 0.f, 0.f, 0.f};
            acc[mt][nt] = z;
        }

    for (int k0 = kbase; k0 < kbase + Klen; k0 += BK) {
        #pragma unroll
        for (int i = 0; i < (ACH + 255) / 256; i++) {
            int chunk = i * 256 + tid;
            if (ACH % 256 == 0 || chunk < ACH) {
                int r = chunk >> 2, cp = chunk & 3;
                int c = cp ^ ((r >> 1) & 3);           // swizzled source chunk
                size_t goff = (size_t)(m0 + r) * lda + k0 + c * 8;
                gload_lds16(Ah + goff, &sAh[chunk * 8]);
                gload_lds16(Al + goff, &sAl[chunk * 8]);
            }
        }
        #pragma unroll
        for (int i = 0; i < (WCH + 255) / 256; i++) {
            int chunk = i * 256 + tid;
            if (WCH % 256 == 0 || chunk < WCH) {
                int r = chunk >> 2, cp = chunk & 3;
                int c = cp ^ ((r >> 1) & 3);
                size_t goff = (size_t)(n0 + r) * ldw + k0 + c * 8;
                gload_lds16(Wh + goff, &sWh[chunk * 8]);
                gload_lds16(Wl + goff, &sWl[chunk * 8]);
            }
        }
        __syncthreads();

        bf16x8 fah[MT], fal[MT], fwh[NT], fwl[NT];
        #pragma unroll
        for (int mt = 0; mt < MT; mt++) {
            int rr = wm0 + mt * 16 + lrow;
            int off = rr * BK + (lq ^ ((rr >> 1) & 3)) * 8;
            fah[mt] = *(const bf16x8*)&sAh[off];
            fal[mt] = *(const bf16x8*)&sAl[off];
        }
        #pragma unroll
        for (int nt = 0; nt < NT; nt++) {
            int rr = wn0 + nt * 16 + lrow;
            int off = rr * BK + (lq ^ ((rr >> 1) & 3)) * 8;
            fwh[nt] = *(const bf16x8*)&sWh[off];
            fwl[nt] = *(const bf16x8*)&sWl[off];
        }
        #pragma unroll
        for (int mt = 0; mt < MT; mt++)
            #pragma unroll
            for (int nt = 0; nt < NT; nt++) {
                acc[mt][nt] = __builtin_amdgcn_mfma_f32_16x16x32_bf16(fah[mt], fwh[nt], acc[mt][nt], 0, 0, 0);
                acc[mt][nt] = __builtin_amdgcn_mfma_f32_16x16x32_bf16(fah[mt], fwl[nt], acc[mt][nt], 0, 0, 0);
                acc[mt][nt] = __builtin_amdgcn_mfma_f32_16x16x32_bf16(fal[mt], fwh[nt], acc[mt][nt], 0, 0, 0);
            }
        __syncthreads();
    }

    // C/D layout: col = lane&15, row = (lane>>4)*4 + reg   [measured m89/m91]
    #pragma unroll
    for (int mt = 0; mt < MT; mt++)
        #pragma unroll
        for (int nt = 0; nt < NT; nt++)
            #pragma unroll
            for (int i = 0; i < 4; i++) {
                int row = m0 + wm0 + mt * 16 + lq * 4 + i;
                int col = n0 + wn0 + nt * 16 + lrow;
                float v = acc[mt][nt][i];
                if (EPI == 2) {
                    float t = v + bias[col];
                    v = fmaxf(t, 0.f) + log1pf(__expf(-fabsf(t)));
                }
                if (col < nclip) C[(size_t)row * ldc + col] = v;
            }
}

// ---------------------------------------------------------------------------
// split-K reduce (4 slices) + optional bf16 hi/lo split for next-layer A
// ---------------------------------------------------------------------------
template<int MODE>
__global__ __launch_bounds__(256) void reduce4(
    const float* __restrict__ part, float* __restrict__ dst,
    unsigned short* __restrict__ hi, unsigned short* __restrict__ lo)
{
    constexpr size_t S = (size_t)MTOK * DMODEL / 4;
    int i = blockIdx.x * 256 + threadIdx.x;
    const float4* p = (const float4*)part;
    float4 a = p[i], b = p[i + S], c = p[i + 2 * S], d = p[i + 3 * S];
    float4 s = {a.x + b.x + c.x + d.x, a.y + b.y + c.y + d.y,
                a.z + b.z + c.z + d.z, a.w + b.w + c.w + d.w};
    if (MODE == 0) {
        ((float4*)dst)[i] = s;
    } else {
        ushort4 h, l;
        splitbf4(s, h, l);
        ((ushort4*)hi)[i] = h;
        ((ushort4*)lo)[i] = l;
    }
}

// ---------------------------------------------------------------------------
// GEMM2 reduce: sum KS2 slices -> xdbl fp32; emit dt cols pre-split.
// ---------------------------------------------------------------------------
__global__ __launch_bounds__(256) void reduce16(
    const float* __restrict__ part, float* __restrict__ xdbl,
    unsigned short* __restrict__ dth, unsigned short* __restrict__ dtl)
{
    constexpr int N4 = MTOK * XDIM / 4;
    constexpr int S4 = MTOK * XDIM / 4;
    int i = blockIdx.x * 256 + threadIdx.x;
    if (i >= N4) return;
    const float4* p = (const float4*)part;
    float4 s = {0.f, 0.f, 0.f, 0.f};
    #pragma unroll
    for (int z = 0; z < KS2; z++) {
        float4 v = p[(size_t)z * S4 + i];
        s.x += v.x; s.y += v.y; s.z += v.z; s.w += v.w;
    }
    ((float4*)xdbl)[i] = s;
    int e = i * 4;
    int col = e % XDIM, row = e / XDIM;
    if (col < DTRANK) {
        ushort4 h, l;
        splitbf4(s, h, l);
        int o = (row * KPAD + col) / 4;
        ((ushort4*)dth)[o] = h;
        ((ushort4*)dtl)[o] = l;
    }
}

// ---------------------------------------------------------------------------
// causal depthwise conv (width 4) + silu -> u emitted as bf16 hi/lo
// ---------------------------------------------------------------------------
__global__ __launch_bounds__(256) void conv_silu_kernel(
    const float* __restrict__ xz, const float* __restrict__ cw,
    const float* __restrict__ cb,
    unsigned short* __restrict__ uh, unsigned short* __restrict__ ul)
{
    int idx = blockIdx.x * 256 + threadIdx.x;   // over MTOK*DINNER
    int d = idx % DINNER;
    int r = idx / DINNER;          // b*SEQLEN + l
    int l = r & (SEQLEN - 1);
    const float* base = xz + (size_t)r * (2 * DINNER) + d;
    float acc = cb[d];
    float w0 = cw[d * 4 + 0], w1 = cw[d * 4 + 1], w2 = cw[d * 4 + 2], w3 = cw[d * 4 + 3];
    if (l >= 3) acc = fmaf(w0, base[-3 * 2 * DINNER], acc);
    if (l >= 2) acc = fmaf(w1, base[-2 * 2 * DINNER], acc);
    if (l >= 1) acc = fmaf(w2, base[-1 * 2 * DINNER], acc);
    acc = fmaf(w3, base[0], acc);
    float uv = acc / (1.f + __expf(-acc));
    unsigned short h, lo_;
    splitbf(uv, h, lo_);
    uh[idx] = h;
    ul[idx] = lo_;
}

// ---------------------------------------------------------------------------
// Fused chunked scan: one kernel does per-chunk (P,q), a Hillis-Steele block
// scan over the 64 chunks (LDS), and the gated y emission. Block = 256 threads
// = 64 chunks x 4 d. Grid = (DINNER/4, BATCH). No global scan intermediates.
// ---------------------------------------------------------------------------
__global__ __launch_bounds__(256, 3) void scan_fused(
    const float* __restrict__ delta,
    const unsigned short* __restrict__ uh, const unsigned short* __restrict__ ul,
    const float* __restrict__ xdbl, const float* __restrict__ xz,
    const float* __restrict__ A_log, const float* __restrict__ Dp,
    unsigned short* __restrict__ yh, unsigned short* __restrict__ yl)
{
    __shared__ float sP[16][256];
    __shared__ float sQ[16][256];
    const int tid = threadIdx.x;
    const int dl = tid & 3, chunk = tid >> 2;
    const int d = blockIdx.x * 4 + dl;
    const int b = blockIdx.y;

    float Arow[16];
    #pragma unroll
    for (int n = 0; n < 16; n++) Arow[n] = -__expf(A_log[d * 16 + n]);

    float p[16], q[16], dc[16];
    #pragma unroll
    for (int n = 0; n < 16; n++) q[n] = 0.f;
    float sdl = 0.f;
    const size_t rowbase = (size_t)b * SEQLEN * DINNER + d;
    const int t0 = chunk * SCLEN;

    // phase 1: per-chunk local scan with h0=0 -> q; sum(delta) -> P
    #pragma unroll
    for (int i = 0; i < SCLEN; i++) {
        int t = t0 + i;
        size_t o = rowbase + (size_t)t * DINNER;
        float dl_ = delta[o];
        float uu = bf2f(uh[o]) + bf2f(ul[o]);
        dc[i] = dl_;
        sdl += dl_;
        float du = dl_ * uu;
        const float4* Bp = (const float4*)(xdbl + (size_t)(b * SEQLEN + t) * XDIM + DTRANK);
        float4 B0 = Bp[0], B1 = Bp[1], B2 = Bp[2], B3 = Bp[3];
        float Bv[16] = {B0.x, B0.y, B0.z, B0.w, B1.x, B1.y, B1.z, B1.w,
                        B2.x, B2.y, B2.z, B2.w, B3.x, B3.y, B3.z, B3.w};
        #pragma unroll
        for (int n = 0; n < 16; n++)
            q[n] = fmaf(__expf(dl_ * Arow[n]), q[n], du * Bv[n]);
    }
    #pragma unroll
    for (int n = 0; n < 16; n++) p[n] = __expf(Arow[n] * sdl);   // prod of dA

    // phase 2: Hillis-Steele scan over chunks per (dl, n); compose
    // (P2,Q2)o(P1,Q1) = (P2*P1, P2*Q1+Q2)
    for (int s = 1; s < SCHUNK; s <<= 1) {
        #pragma unroll
        for (int n = 0; n < 16; n++) {
            sP[n][tid] = p[n];
            sQ[n][tid] = q[n];
        }
        __syncthreads();
        if (chunk >= s) {
            #pragma unroll
            for (int n = 0; n < 16; n++) {
                float pp = sP[n][tid - 4 * s];
                float qq = sQ[n][tid - 4 * s];
                q[n] = fmaf(p[n], qq, q[n]);
                p[n] *= pp;
            }
        }
        __syncthreads();
    }
    // exclusive prefix -> h at chunk start
    #pragma unroll
    for (int n = 0; n < 16; n++) sQ[n][tid] = q[n];
    __syncthreads();
    float h[16];
    #pragma unroll
    for (int n = 0; n < 16; n++) h[n] = (chunk == 0) ? 0.f : sQ[n][tid - 4];

    // phase 3: replay chunk with known h-init, emit gated y (bf16 hi/lo)
    const float Dpar = Dp[d];
    #pragma unroll
    for (int i = 0; i < SCLEN; i++) {
        int t = t0 + i;
        size_t o = rowbase + (size_t)t * DINNER;
        float dl_ = dc[i];
        float uu = bf2f(uh[o]) + bf2f(ul[o]);
        float du = dl_ * uu;
        const float4* Bp = (const float4*)(xdbl + (size_t)(b * SEQLEN + t) * XDIM + DTRANK);
        float4 B0 = Bp[0], B1 = Bp[1], B2 = Bp[2], B3 = Bp[3];
        float4 C0 = Bp[4], C1 = Bp[5], C2 = Bp[6], C3 = Bp[7];
        float Bv[16] = {B0.x, B0.y, B0.z, B0.w, B1.x, B1.y, B1.z, B1.w,
                        B2.x, B2.y, B2.z, B2.w, B3.x, B3.y, B3.z, B3.w};
        float Cv[16] = {C0.x, C0.y, C0.z, C0.w, C1.x, C1.y, C1.z, C1.w,
                        C2.x, C2.y, C2.z, C2.w, C3.x, C3.y, C3.z, C3.w};
        float yt = 0.f;
        #pragma unroll
        for (int n = 0; n < 16; n++) {
            float dA = __expf(dl_ * Arow[n]);
            h[n] = fmaf(dA, h[n], du * Bv[n]);
            yt = fmaf(h[n], Cv[n], yt);
        }
        yt = fmaf(uu, Dpar, yt);
        float z = xz[(size_t)(b * SEQLEN + t) * (2 * DINNER) + DINNER + d];
        float sz = z / (1.f + __expf(-z));
        float yv = yt * sz;
        unsigned short hh, ll;
        splitbf(yv, hh, ll);
        yh[o] = hh;
        yl[o] = ll;
    }
}

// ---------------------------------------------------------------------------
extern "C" void kernel_launch(void* const* d_in, const int* in_sizes, int n_in,
                              void* d_out, int out_size, void* d_ws, size_t ws_size,
                              hipStream_t stream) {
    const float* x    = (const float*)d_in[0];
    const float* ipw  = (const float*)d_in[1];
    const float* cw   = (const float*)d_in[2];
    const float* cb   = (const float*)d_in[3];
    const float* xpw  = (const float*)d_in[4];
    const float* dpw  = (const float*)d_in[5];
    const float* dpb  = (const float*)d_in[6];
    const float* alog = (const float*)d_in[7];
    const float* dpar = (const float*)d_in[8];
    const float* opw  = (const float*)d_in[9];
    float* out = (float*)d_out;

    char* ws = (char*)d_ws;
    float* xz    = (float*)ws;            ws += (size_t)MTOK * 2 * DINNER * 4;   // 25.2 MB
    float* delta = (float*)ws;            ws += (size_t)MTOK * DINNER * 4;       // 12.6 MB
    float* xdbl  = (float*)ws;            ws += (size_t)MTOK * XDIM * 4;         // 0.66 MB
    float* part  = (float*)ws;            ws += (size_t)4 * MTOK * DMODEL * 4;   // 25.2 MB (also holds GEMM2 partials 10.5 MB)
    unsigned short* ah  = (unsigned short*)ws; ws += (size_t)MTOK * DMODEL * 2;
    unsigned short* al  = (unsigned short*)ws; ws += (size_t)MTOK * DMODEL * 2;
    unsigned short* yh  = (unsigned short*)ws; ws += (size_t)MTOK * DINNER * 2;
    unsigned short* yl  = (unsigned short*)ws; ws += (size_t)MTOK * DINNER * 2;
    unsigned short* uh  = (unsigned short*)ws; ws += (size_t)MTOK * DINNER * 2;
    unsigned short* ul  = (unsigned short*)ws; ws += (size_t)MTOK * DINNER * 2;
    unsigned short* wih = (unsigned short*)ws; ws += (size_t)2 * DINNER * DMODEL * 2;
    unsigned short* wil = (unsigned short*)ws; ws += (size_t)2 * DINNER * DMODEL * 2;
    unsigned short* woh = (unsigned short*)ws; ws += (size_t)DMODEL * DINNER * 2;
    unsigned short* wol = (unsigned short*)ws; ws += (size_t)DMODEL * DINNER * 2;
    unsigned short* wxh = (unsigned short*)ws; ws += (size_t)NPAD * DINNER * 2;
    unsigned short* wxl = (unsigned short*)ws; ws += (size_t)NPAD * DINNER * 2;
    unsigned short* wdh = (unsigned short*)ws; ws += (size_t)DINNER * KPAD * 2;
    unsigned short* wdl = (unsigned short*)ws; ws += (size_t)DINNER * KPAD * 2;
    unsigned short* dth = (unsigned short*)ws; ws += (size_t)MTOK * KPAD * 2;
    unsigned short* dtl = (unsigned short*)ws; ws += (size_t)MTOK * KPAD * 2;

    for (int L = 0; L < NL; L++) {
        const float* ipw_l  = ipw  + (size_t)L * 2 * DINNER * DMODEL;
        const float* cw_l   = cw   + (size_t)L * DINNER * DCONV;
        const float* cb_l   = cb   + (size_t)L * DINNER;
        const float* xpw_l  = xpw  + (size_t)L * XDIM * DINNER;
        const float* dpw_l  = dpw  + (size_t)L * DINNER * DTRANK;
        const float* dpb_l  = dpb  + (size_t)L * DINNER;
        const float* alog_l = alog + (size_t)L * DINNER * DSTATE;
        const float* dpar_l = dpar + (size_t)L * DINNER;
        const float* opw_l  = opw  + (size_t)L * DMODEL * DINNER;

        if (L == 0) {
            prep_kernel<1><<<(N_PREP + N_XSPL) / 256, 256, 0, stream>>>(
                ipw_l, opw_l, xpw_l, dpw_l, x,
                wih, wil, woh, wol, wxh, wxl, wdh, wdl, dth, dtl, ah, al);
        } else {
            prep_kernel<0><<<N_PREP / 256, 256, 0, stream>>>(
                ipw_l, opw_l, xpw_l, dpw_l, x,
                wih, wil, woh, wol, wxh, wxl, wdh, wdl, dth, dtl, ah, al);
        }

        // GEMM1: xz[2048,3072] = A @ ipw^T   (512 blocks = 2/CU)
        gemm_pre<128, 96, 0><<<dim3(2 * DINNER / 96, MTOK / 128, 1), 256, 0, stream>>>(
            ah, al, DMODEL, wih, wil, DMODEL, xz, 2 * DINNER, DMODEL, 0, 1 << 30, nullptr);

        // conv + silu -> u (bf16 hi/lo)
        conv_silu_kernel<<<(MTOK * DINNER) / 256, 256, 0, stream>>>(xz, cw_l, cb_l, uh, ul);

        // GEMM2 (split-K=16): part[z][2048,80] = u-slice @ xpw-slice^T  (512 blocks)
        gemm_pre<64, 96, 0><<<dim3(1, MTOK / 64, KS2), 256, 0, stream>>>(
            uh, ul, DINNER, wxh, wxl, DINNER, part, XDIM,
            DINNER / KS2, (size_t)MTOK * XDIM, XDIM, nullptr);
        reduce16<<<(MTOK * XDIM / 4 + 255) / 256, 256, 0, stream>>>(part, xdbl, dth, dtl);

        // GEMM3: delta = softplus(dt @ dpw^T + dpb)   (K padded to 64)
        gemm_pre<128, 96, 2><<<dim3(DINNER / 96, MTOK / 128, 1), 256, 0, stream>>>(
            dth, dtl, KPAD, wdh, wdl, KPAD, delta, DINNER, KPAD, 0, 1 << 30, dpb_l);

        // fused scan -> y (bf16 hi/lo)
        scan_fused<<<dim3(DINNER / 4, BATCH), 256, 0, stream>>>(
            delta, uh, ul, xdbl, xz, alog_l, dpar_l, yh, yl);

        // GEMM4 (split-K=4): part[z][2048,768] = y @ opw^T  (512 blocks)
        gemm_pre<128, 96, 0><<<dim3(DMODEL / 96, MTOK / 128, 4), 256, 0, stream>>>(
            yh, yl, DINNER, woh, wol, DINNER, part, DMODEL,
            DINNER / 4, (size_t)MTOK * DMODEL, 1 << 30, nullptr);

        // reduce split-K; L<3 -> next layer's A (bf16 hi/lo), L==3 -> fp32 out
        int rblocks = MTOK * DMODEL / 4 / 256;
        if (L == NL - 1) {
            reduce4<0><<<rblocks, 256, 0, stream>>>(part, out, nullptr, nullptr);
        } else {
            reduce4<1><<<rblocks, 256, 0, stream>>>(part, nullptr, ah, al);
        }
    }
    (void)in_sizes; (void)n_in; (void)out_size; (void)ws_size;
}

// Round 6
// 748.151 us; speedup vs baseline: 2.3326x; 2.3326x over previous
//
#include <hip/hip_runtime.h>
#include <math.h>

#define NL 4
#define DMODEL 768
#define DINNER 1536
#define DSTATE 16
#define DCONV 4
#define DTRANK 48
#define BATCH 2
#define SEQLEN 1024
#define MTOK (BATCH*SEQLEN)      // 2048
#define XDIM 80                  // DT_RANK + 2*D_STATE
#define KPAD 64                  // DTRANK padded for MFMA
#define NPAD 96                  // XDIM padded for MFMA (3x32)
#define KS2 16                   // split-K slices for GEMM2
#define NCHUNK 64
#define NCSHIFT 6
#define CLEN 16                  // SEQLEN/NCHUNK
#define CHSTRIDE (BATCH*16*DINNER)   // 49152

typedef __bf16 bf16x8 __attribute__((ext_vector_type(8)));
typedef float f32x4 __attribute__((ext_vector_type(4)));

__device__ __forceinline__ void splitbf(float f, unsigned short& hi, unsigned short& lo) {
    unsigned uh = __float_as_uint(f);
    unsigned rh = uh + (0x7fffu + ((uh >> 16) & 1u));
    unsigned short h = (unsigned short)(rh >> 16);
    float fh = __uint_as_float(((unsigned)h) << 16);
    float r = f - fh;
    unsigned ul = __float_as_uint(r);
    unsigned rl = ul + (0x7fffu + ((ul >> 16) & 1u));
    hi = h;
    lo = (unsigned short)(rl >> 16);
}

__device__ __forceinline__ void splitbf4(float4 v, ushort4& h, ushort4& l) {
    splitbf(v.x, h.x, l.x);
    splitbf(v.y, h.y, l.y);
    splitbf(v.z, h.z, l.z);
    splitbf(v.w, h.w, l.w);
}

__device__ __forceinline__ float bf2f(unsigned short h) {
    return __uint_as_float(((unsigned)h) << 16);
}

__device__ __forceinline__ void gload_lds16(const void* g, void* l) {
    __builtin_amdgcn_global_load_lds(
        (const __attribute__((address_space(1))) unsigned*)g,
        (__attribute__((address_space(3))) unsigned*)l, 16, 0, 0);
}

// ---------------------------------------------------------------------------
// Per-layer prep: all weight splits (+padding) and dt pad-zero in ONE kernel.
// ---------------------------------------------------------------------------
#define N_IPW (2 * DINNER * DMODEL / 4)
#define N_OPW (DMODEL * DINNER / 4)
#define N_XPW (NPAD * DINNER / 4)
#define N_DPW (DINNER * KPAD / 4)
#define N_DTP (MTOK * (KPAD - DTRANK) / 4)
#define N_PREP (N_IPW + N_OPW + N_XPW + N_DPW + N_DTP)
#define N_XSPL (MTOK * DMODEL / 4)

template<int WITHX>
__global__ __launch_bounds__(256) void prep_kernel(
    const float* __restrict__ ipw_l, const float* __restrict__ opw_l,
    const float* __restrict__ xpw_l, const float* __restrict__ dpw_l,
    const float* __restrict__ x,
    unsigned short* __restrict__ wih, unsigned short* __restrict__ wil,
    unsigned short* __restrict__ woh, unsigned short* __restrict__ wol,
    unsigned short* __restrict__ wxh, unsigned short* __restrict__ wxl,
    unsigned short* __restrict__ wdh, unsigned short* __restrict__ wdl,
    unsigned short* __restrict__ dth, unsigned short* __restrict__ dtl,
    unsigned short* __restrict__ ah, unsigned short* __restrict__ al)
{
    int i = blockIdx.x * 256 + threadIdx.x;
    if (i < N_IPW) {
        float4 v = ((const float4*)ipw_l)[i];
        ushort4 h, l;
        splitbf4(v, h, l);
        ((ushort4*)wih)[i] = h;
        ((ushort4*)wil)[i] = l;
        return;
    }
    i -= N_IPW;
    if (i < N_OPW) {
        float4 v = ((const float4*)opw_l)[i];
        ushort4 h, l;
        splitbf4(v, h, l);
        ((ushort4*)woh)[i] = h;
        ((ushort4*)wol)[i] = l;
        return;
    }
    i -= N_OPW;
    if (i < N_XPW) {
        int e = i * 4;
        int row = e / DINNER, col = e % DINNER;
        ushort4 h = {0, 0, 0, 0}, l = {0, 0, 0, 0};
        if (row < XDIM) {
            float4 v = *(const float4*)(xpw_l + (size_t)row * DINNER + col);
            splitbf4(v, h, l);
        }
        ((ushort4*)wxh)[i] = h;
        ((ushort4*)wxl)[i] = l;
        return;
    }
    i -= N_XPW;
    if (i < N_DPW) {
        int e = i * 4;
        int row = e >> 6, col = e & 63;
        ushort4 h = {0, 0, 0, 0}, l = {0, 0, 0, 0};
        if (col < DTRANK) {
            float4 v = *(const float4*)(dpw_l + (size_t)row * DTRANK + col);
            splitbf4(v, h, l);
        }
        ((ushort4*)wdh)[i] = h;
        ((ushort4*)wdl)[i] = l;
        return;
    }
    i -= N_DPW;
    if (i < N_DTP) {
        int e = i * 4;
        int row = e >> 4, col = DTRANK + (e & 15);
        int o = (row * KPAD + col) / 4;
        ushort4 z = {0, 0, 0, 0};
        ((ushort4*)dth)[o] = z;
        ((ushort4*)dtl)[o] = z;
        return;
    }
    if (WITHX) {
        i -= N_DTP;
        if (i < N_XSPL) {
            float4 v = ((const float4*)x)[i];
            ushort4 h, l;
            splitbf4(v, h, l);
            ((ushort4*)ah)[i] = h;
            ((ushort4*)al)[i] = l;
        }
    }
}

// ---------------------------------------------------------------------------
// Pre-split 3-pass bf16 MFMA GEMM, XOR-swizzled LDS (bank-conflict-free).
// ---------------------------------------------------------------------------
template<int BM, int BN, int EPI>
__global__ __launch_bounds__(256, 2) void gemm_pre(
    const unsigned short* __restrict__ Ah, const unsigned short* __restrict__ Al, int lda,
    const unsigned short* __restrict__ Wh, const unsigned short* __restrict__ Wl, int ldw,
    float* __restrict__ C, int ldc, int Klen, size_t zstride, int nclip,
    const float* __restrict__ bias)
{
    constexpr int BK = 32;
    constexpr int MT = BM / 32, NT = BN / 32;
    constexpr int ACH = BM * 4;
    constexpr int WCH = BN * 4;
    __shared__ unsigned short sAh[BM * BK];
    __shared__ unsigned short sAl[BM * BK];
    __shared__ unsigned short sWh[BN * BK];
    __shared__ unsigned short sWl[BN * BK];

    const int tid = threadIdx.x;
    const int m0 = blockIdx.y * BM, n0 = blockIdx.x * BN;
    const int kbase = blockIdx.z * Klen;
    C += (size_t)blockIdx.z * zstride;
    const int lane = tid & 63, wave = tid >> 6;
    const int wr = wave >> 1, wc = wave & 1;
    const int wm0 = wr * (BM / 2), wn0 = wc * (BN / 2);
    const int lrow = lane & 15, lq = lane >> 4;

    f32x4 acc[MT][NT];
    #pragma unroll
    for (int mt = 0; mt < MT; mt++)
        #pragma unroll
        for (int nt = 0; nt < NT; nt++) {
            f32x4 z = {0.f, 0.f, 0.f, 0.f};
            acc[mt][nt] = z;
        }

    for (int k0 = kbase; k0 < kbase + Klen; k0 += BK) {
        #pragma unroll
        for (int i = 0; i < (ACH + 255) / 256; i++) {
            int chunk = i * 256 + tid;
            if (ACH % 256 == 0 || chunk < ACH) {
                int r = chunk >> 2, cp = chunk & 3;
                int c = cp ^ ((r >> 1) & 3);
                size_t goff = (size_t)(m0 + r) * lda + k0 + c * 8;
                gload_lds16(Ah + goff, &sAh[chunk * 8]);
                gload_lds16(Al + goff, &sAl[chunk * 8]);
            }
        }
        #pragma unroll
        for (int i = 0; i < (WCH + 255) / 256; i++) {
            int chunk = i * 256 + tid;
            if (WCH % 256 == 0 || chunk < WCH) {
                int r = chunk >> 2, cp = chunk & 3;
                int c = cp ^ ((r >> 1) & 3);
                size_t goff = (size_t)(n0 + r) * ldw + k0 + c * 8;
                gload_lds16(Wh + goff, &sWh[chunk * 8]);
                gload_lds16(Wl + goff, &sWl[chunk * 8]);
            }
        }
        __syncthreads();

        bf16x8 fah[MT], fal[MT], fwh[NT], fwl[NT];
        #pragma unroll
        for (int mt = 0; mt < MT; mt++) {
            int rr = wm0 + mt * 16 + lrow;
            int off = rr * BK + (lq ^ ((rr >> 1) & 3)) * 8;
            fah[mt] = *(const bf16x8*)&sAh[off];
            fal[mt] = *(const bf16x8*)&sAl[off];
        }
        #pragma unroll
        for (int nt = 0; nt < NT; nt++) {
            int rr = wn0 + nt * 16 + lrow;
            int off = rr * BK + (lq ^ ((rr >> 1) & 3)) * 8;
            fwh[nt] = *(const bf16x8*)&sWh[off];
            fwl[nt] = *(const bf16x8*)&sWl[off];
        }
        #pragma unroll
        for (int mt = 0; mt < MT; mt++)
            #pragma unroll
            for (int nt = 0; nt < NT; nt++) {
                acc[mt][nt] = __builtin_amdgcn_mfma_f32_16x16x32_bf16(fah[mt], fwh[nt], acc[mt][nt], 0, 0, 0);
                acc[mt][nt] = __builtin_amdgcn_mfma_f32_16x16x32_bf16(fah[mt], fwl[nt], acc[mt][nt], 0, 0, 0);
                acc[mt][nt] = __builtin_amdgcn_mfma_f32_16x16x32_bf16(fal[mt], fwh[nt], acc[mt][nt], 0, 0, 0);
            }
        __syncthreads();
    }

    // C/D layout: col = lane&15, row = (lane>>4)*4 + reg   [measured m89/m91]
    #pragma unroll
    for (int mt = 0; mt < MT; mt++)
        #pragma unroll
        for (int nt = 0; nt < NT; nt++)
            #pragma unroll
            for (int i = 0; i < 4; i++) {
                int row = m0 + wm0 + mt * 16 + lq * 4 + i;
                int col = n0 + wn0 + nt * 16 + lrow;
                float v = acc[mt][nt][i];
                if (EPI == 2) {
                    float t = v + bias[col];
                    v = fmaxf(t, 0.f) + log1pf(__expf(-fabsf(t)));
                }
                if (col < nclip) C[(size_t)row * ldc + col] = v;
            }
}

// ---------------------------------------------------------------------------
// split-K reduce (4 slices) + optional bf16 hi/lo split for next-layer A
// ---------------------------------------------------------------------------
template<int MODE>
__global__ __launch_bounds__(256) void reduce4(
    const float* __restrict__ part, float* __restrict__ dst,
    unsigned short* __restrict__ hi, unsigned short* __restrict__ lo)
{
    constexpr size_t S = (size_t)MTOK * DMODEL / 4;
    int i = blockIdx.x * 256 + threadIdx.x;
    const float4* p = (const float4*)part;
    float4 a = p[i], b = p[i + S], c = p[i + 2 * S], d = p[i + 3 * S];
    float4 s = {a.x + b.x + c.x + d.x, a.y + b.y + c.y + d.y,
                a.z + b.z + c.z + d.z, a.w + b.w + c.w + d.w};
    if (MODE == 0) {
        ((float4*)dst)[i] = s;
    } else {
        ushort4 h, l;
        splitbf4(s, h, l);
        ((ushort4*)hi)[i] = h;
        ((ushort4*)lo)[i] = l;
    }
}

// ---------------------------------------------------------------------------
// GEMM2 reduce: sum KS2 slices -> xdbl fp32; emit dt cols pre-split.
// ---------------------------------------------------------------------------
__global__ __launch_bounds__(256) void reduce16(
    const float* __restrict__ part, float* __restrict__ xdbl,
    unsigned short* __restrict__ dth, unsigned short* __restrict__ dtl)
{
    constexpr int N4 = MTOK * XDIM / 4;
    constexpr int S4 = MTOK * XDIM / 4;
    int i = blockIdx.x * 256 + threadIdx.x;
    if (i >= N4) return;
    const float4* p = (const float4*)part;
    float4 s = {0.f, 0.f, 0.f, 0.f};
    #pragma unroll
    for (int z = 0; z < KS2; z++) {
        float4 v = p[(size_t)z * S4 + i];
        s.x += v.x; s.y += v.y; s.z += v.z; s.w += v.w;
    }
    ((float4*)xdbl)[i] = s;
    int e = i * 4;
    int col = e % XDIM, row = e / XDIM;
    if (col < DTRANK) {
        ushort4 h, l;
        splitbf4(s, h, l);
        int o = (row * KPAD + col) / 4;
        ((ushort4*)dth)[o] = h;
        ((ushort4*)dtl)[o] = l;
    }
}

// ---------------------------------------------------------------------------
// causal depthwise conv (width 4) + silu -> u emitted as bf16 hi/lo
// ---------------------------------------------------------------------------
__global__ __launch_bounds__(256) void conv_silu_kernel(
    const float* __restrict__ xz, const float* __restrict__ cw,
    const float* __restrict__ cb,
    unsigned short* __restrict__ uh, unsigned short* __restrict__ ul)
{
    int idx = blockIdx.x * 256 + threadIdx.x;   // over MTOK*DINNER
    int d = idx % DINNER;
    int r = idx / DINNER;          // b*SEQLEN + l
    int l = r & (SEQLEN - 1);
    const float* base = xz + (size_t)r * (2 * DINNER) + d;
    float acc = cb[d];
    float w0 = cw[d * 4 + 0], w1 = cw[d * 4 + 1], w2 = cw[d * 4 + 2], w3 = cw[d * 4 + 3];
    if (l >= 3) acc = fmaf(w0, base[-3 * 2 * DINNER], acc);
    if (l >= 2) acc = fmaf(w1, base[-2 * 2 * DINNER], acc);
    if (l >= 1) acc = fmaf(w2, base[-1 * 2 * DINNER], acc);
    acc = fmaf(w3, base[0], acc);
    float uv = acc / (1.f + __expf(-acc));
    unsigned short h, lo_;
    splitbf(uv, h, lo_);
    uh[idx] = h;
    ul[idx] = lo_;
}

// ---------------------------------------------------------------------------
// Chunked parallel scan (3 passes), NCHUNK=64. [round-4 proven: VGPR 36,
// no spill; fused variant spilled to scratch -> 855 MB HBM, reverted]
// ---------------------------------------------------------------------------
__global__ __launch_bounds__(256, 4) void scan_pass1(
    const float* __restrict__ delta,
    const unsigned short* __restrict__ uh, const unsigned short* __restrict__ ul,
    const float* __restrict__ xdbl, const float* __restrict__ A_log,
    float* __restrict__ pbuf, float* __restrict__ qbuf)
{
    int gid = blockIdx.x * 256 + threadIdx.x;  // BATCH*NCHUNK*DINNER
    int d = gid % DINNER;
    int r = gid / DINNER;
    int chunk = r & (NCHUNK - 1);
    int b = r >> NCSHIFT;
    float Arow[16], q[16];
    #pragma unroll
    for (int n = 0; n < 16; n++) {
        Arow[n] = -__expf(A_log[d * 16 + n]);
        q[n] = 0.f;
    }
    float sdl = 0.f;
    size_t rowbase = (size_t)b * SEQLEN * DINNER + d;
    int t0 = chunk * CLEN;
    #pragma unroll 2
    for (int i = 0; i < CLEN; i++) {
        int t = t0 + i;
        size_t o = rowbase + (size_t)t * DINNER;
        float dl = delta[o];
        float uu = bf2f(uh[o]) + bf2f(ul[o]);
        float du = dl * uu;
        sdl += dl;
        const float* Bp = xdbl + (size_t)(b * SEQLEN + t) * XDIM + DTRANK;
        #pragma unroll
        for (int n = 0; n < 16; n++) {
            float dA = __expf(dl * Arow[n]);
            q[n] = fmaf(dA, q[n], du * Bp[n]);
        }
    }
    size_t off = (size_t)((chunk * BATCH + b) * 16) * DINNER + d;
    #pragma unroll
    for (int n = 0; n < 16; n++) {
        pbuf[off + (size_t)n * DINNER] = __expf(Arow[n] * sdl);   // prod of dA
        qbuf[off + (size_t)n * DINNER] = q[n];
    }
}

__global__ __launch_bounds__(256) void scan_pass2(
    const float* __restrict__ pbuf, const float* __restrict__ qbuf,
    float* __restrict__ hinit)
{
    int gid = blockIdx.x * 256 + threadIdx.x;   // BATCH*16*DINNER
    float h = 0.f;
    #pragma unroll 4
    for (int c = 0; c < NCHUNK; c++) {
        size_t o = (size_t)c * CHSTRIDE + gid;
        hinit[o] = h;
        h = fmaf(pbuf[o], h, qbuf[o]);
    }
}

__global__ __launch_bounds__(256, 4) void scan_pass3(
    const float* __restrict__ delta,
    const unsigned short* __restrict__ uh, const unsigned short* __restrict__ ul,
    const float* __restrict__ xdbl, const float* __restrict__ xz,
    const float* __restrict__ A_log, const float* __restrict__ Dp,
    const float* __restrict__ hinit,
    unsigned short* __restrict__ yh, unsigned short* __restrict__ yl)
{
    int gid = blockIdx.x * 256 + threadIdx.x;
    int d = gid % DINNER;
    int r = gid / DINNER;
    int chunk = r & (NCHUNK - 1);
    int b = r >> NCSHIFT;
    float Arow[16], h[16];
    #pragma unroll
    for (int n = 0; n < 16; n++) Arow[n] = -__expf(A_log[d * 16 + n]);
    size_t hoff = (size_t)chunk * CHSTRIDE + (size_t)(b * 16) * DINNER + d;
    #pragma unroll
    for (int n = 0; n < 16; n++) h[n] = hinit[hoff + (size_t)n * DINNER];
    float Dpar = Dp[d];
    size_t rowbase = (size_t)b * SEQLEN * DINNER + d;
    int t0 = chunk * CLEN;
    #pragma unroll 2
    for (int i = 0; i < CLEN; i++) {
        int t = t0 + i;
        size_t o = rowbase + (size_t)t * DINNER;
        float dl = delta[o];
        float uu = bf2f(uh[o]) + bf2f(ul[o]);
        float du = dl * uu;
        const float* Bp = xdbl + (size_t)(b * SEQLEN + t) * XDIM + DTRANK;
        float yt = 0.f;
        #pragma unroll
        for (int n = 0; n < 16; n++) {
            float dA = __expf(dl * Arow[n]);
            h[n] = fmaf(dA, h[n], du * Bp[n]);
            yt = fmaf(h[n], Bp[16 + n], yt);
        }
        yt = fmaf(uu, Dpar, yt);
        float z = xz[(size_t)(b * SEQLEN + t) * (2 * DINNER) + DINNER + d];
        float sz = z / (1.f + __expf(-z));
        float yv = yt * sz;
        unsigned short hh, ll;
        splitbf(yv, hh, ll);
        yh[o] = hh;
        yl[o] = ll;
    }
}

// ---------------------------------------------------------------------------
extern "C" void kernel_launch(void* const* d_in, const int* in_sizes, int n_in,
                              void* d_out, int out_size, void* d_ws, size_t ws_size,
                              hipStream_t stream) {
    const float* x    = (const float*)d_in[0];
    const float* ipw  = (const float*)d_in[1];
    const float* cw   = (const float*)d_in[2];
    const float* cb   = (const float*)d_in[3];
    const float* xpw  = (const float*)d_in[4];
    const float* dpw  = (const float*)d_in[5];
    const float* dpb  = (const float*)d_in[6];
    const float* alog = (const float*)d_in[7];
    const float* dpar = (const float*)d_in[8];
    const float* opw  = (const float*)d_in[9];
    float* out = (float*)d_out;

    char* ws = (char*)d_ws;
    float* xz    = (float*)ws;            ws += (size_t)MTOK * 2 * DINNER * 4;
    float* delta = (float*)ws;            ws += (size_t)MTOK * DINNER * 4;
    float* xdbl  = (float*)ws;            ws += (size_t)MTOK * XDIM * 4;
    float* pbuf  = (float*)ws;            ws += (size_t)NCHUNK * CHSTRIDE * 4;
    float* qbuf  = (float*)ws;            ws += (size_t)NCHUNK * CHSTRIDE * 4;
    float* hinit = (float*)ws;            ws += (size_t)NCHUNK * CHSTRIDE * 4;
    float* part  = (float*)ws;            ws += (size_t)4 * MTOK * DMODEL * 4;
    unsigned short* ah  = (unsigned short*)ws; ws += (size_t)MTOK * DMODEL * 2;
    unsigned short* al  = (unsigned short*)ws; ws += (size_t)MTOK * DMODEL * 2;
    unsigned short* yh  = (unsigned short*)ws; ws += (size_t)MTOK * DINNER * 2;
    unsigned short* yl  = (unsigned short*)ws; ws += (size_t)MTOK * DINNER * 2;
    unsigned short* uh  = (unsigned short*)ws; ws += (size_t)MTOK * DINNER * 2;
    unsigned short* ul  = (unsigned short*)ws; ws += (size_t)MTOK * DINNER * 2;
    unsigned short* wih = (unsigned short*)ws; ws += (size_t)2 * DINNER * DMODEL * 2;
    unsigned short* wil = (unsigned short*)ws; ws += (size_t)2 * DINNER * DMODEL * 2;
    unsigned short* woh = (unsigned short*)ws; ws += (size_t)DMODEL * DINNER * 2;
    unsigned short* wol = (unsigned short*)ws; ws += (size_t)DMODEL * DINNER * 2;
    unsigned short* wxh = (unsigned short*)ws; ws += (size_t)NPAD * DINNER * 2;
    unsigned short* wxl = (unsigned short*)ws; ws += (size_t)NPAD * DINNER * 2;
    unsigned short* wdh = (unsigned short*)ws; ws += (size_t)DINNER * KPAD * 2;
    unsigned short* wdl = (unsigned short*)ws; ws += (size_t)DINNER * KPAD * 2;
    unsigned short* dth = (unsigned short*)ws; ws += (size_t)MTOK * KPAD * 2;
    unsigned short* dtl = (unsigned short*)ws; ws += (size_t)MTOK * KPAD * 2;

    for (int L = 0; L < NL; L++) {
        const float* ipw_l  = ipw  + (size_t)L * 2 * DINNER * DMODEL;
        const float* cw_l   = cw   + (size_t)L * DINNER * DCONV;
        const float* cb_l   = cb   + (size_t)L * DINNER;
        const float* xpw_l  = xpw  + (size_t)L * XDIM * DINNER;
        const float* dpw_l  = dpw  + (size_t)L * DINNER * DTRANK;
        const float* dpb_l  = dpb  + (size_t)L * DINNER;
        const float* alog_l = alog + (size_t)L * DINNER * DSTATE;
        const float* dpar_l = dpar + (size_t)L * DINNER;
        const float* opw_l  = opw  + (size_t)L * DMODEL * DINNER;

        if (L == 0) {
            prep_kernel<1><<<(N_PREP + N_XSPL) / 256, 256, 0, stream>>>(
                ipw_l, opw_l, xpw_l, dpw_l, x,
                wih, wil, woh, wol, wxh, wxl, wdh, wdl, dth, dtl, ah, al);
        } else {
            prep_kernel<0><<<N_PREP / 256, 256, 0, stream>>>(
                ipw_l, opw_l, xpw_l, dpw_l, x,
                wih, wil, woh, wol, wxh, wxl, wdh, wdl, dth, dtl, ah, al);
        }

        // GEMM1: xz[2048,3072] = A @ ipw^T   (512 blocks = 2/CU)
        gemm_pre<128, 96, 0><<<dim3(2 * DINNER / 96, MTOK / 128, 1), 256, 0, stream>>>(
            ah, al, DMODEL, wih, wil, DMODEL, xz, 2 * DINNER, DMODEL, 0, 1 << 30, nullptr);

        // conv + silu -> u (bf16 hi/lo)
        conv_silu_kernel<<<(MTOK * DINNER) / 256, 256, 0, stream>>>(xz, cw_l, cb_l, uh, ul);

        // GEMM2 (split-K=16): part[z][2048,80] = u-slice @ xpw-slice^T  (512 blocks)
        gemm_pre<64, 96, 0><<<dim3(1, MTOK / 64, KS2), 256, 0, stream>>>(
            uh, ul, DINNER, wxh, wxl, DINNER, part, XDIM,
            DINNER / KS2, (size_t)MTOK * XDIM, XDIM, nullptr);
        reduce16<<<(MTOK * XDIM / 4 + 255) / 256, 256, 0, stream>>>(part, xdbl, dth, dtl);

        // GEMM3: delta = softplus(dt @ dpw^T + dpb)   (K padded to 64)
        gemm_pre<128, 96, 2><<<dim3(DINNER / 96, MTOK / 128, 1), 256, 0, stream>>>(
            dth, dtl, KPAD, wdh, wdl, KPAD, delta, DINNER, KPAD, 0, 1 << 30, dpb_l);

        // chunked scan (3 passes); pass3 emits y as bf16 hi/lo
        scan_pass1<<<(BATCH * NCHUNK * DINNER) / 256, 256, 0, stream>>>(
            delta, uh, ul, xdbl, alog_l, pbuf, qbuf);
        scan_pass2<<<CHSTRIDE / 256, 256, 0, stream>>>(pbuf, qbuf, hinit);
        scan_pass3<<<(BATCH * NCHUNK * DINNER) / 256, 256, 0, stream>>>(
            delta, uh, ul, xdbl, xz, alog_l, dpar_l, hinit, yh, yl);

        // GEMM4 (split-K=4): part[z][2048,768] = y @ opw^T  (512 blocks)
        gemm_pre<128, 96, 0><<<dim3(DMODEL / 96, MTOK / 128, 4), 256, 0, stream>>>(
            yh, yl, DINNER, woh, wol, DINNER, part, DMODEL,
            DINNER / 4, (size_t)MTOK * DMODEL, 1 << 30, nullptr);

        // reduce split-K; L<3 -> next layer's A (bf16 hi/lo), L==3 -> fp32 out
        int rblocks = MTOK * DMODEL / 4 / 256;
        if (L == NL - 1) {
            reduce4<0><<<rblocks, 256, 0, stream>>>(part, out, nullptr, nullptr);
        } else {
            reduce4<1><<<rblocks, 256, 0, stream>>>(part, nullptr, ah, al);
        }
    }
    (void)in_sizes; (void)n_in; (void)out_size; (void)ws_size;
}